// Round 1
// baseline (1056.413 us; speedup 1.0000x reference)
//
#include <hip/hip_runtime.h>
#include <cstdint>

// ---------------------------------------------------------------------------
// Problem constants
//   x: (16, 512, 96, 96) fp32; in_proj_w: (1536,512); in_proj_b: (1536,)
//   out_w: (512,512); out_b: (512,)
//   Padded grid 100x100, roll +2; windows 4x4 -> 625/image; token
//   m = g*10000 + hh*100 + ww  (hh,ww in rolled/padded coords)
// ---------------------------------------------------------------------------

typedef __attribute__((ext_vector_type(8))) __bf16 bf16x8;
typedef __attribute__((ext_vector_type(8))) uint16_t u16x8;
typedef __attribute__((ext_vector_type(4))) float f32x4;

__device__ __forceinline__ uint16_t f2bf(float f) {
  union { float f; uint32_t u; } c; c.f = f;
  uint32_t r = c.u + 0x7FFFu + ((c.u >> 16) & 1u);  // RNE
  return (uint16_t)(r >> 16);
}
__device__ __forceinline__ float bf2f(uint16_t u) {
  union { uint32_t u; float f; } c; c.u = ((uint32_t)u) << 16;
  return c.f;
}

// global -> LDS async copy, 16B per lane (wave-uniform LDS base + lane*16)
__device__ __forceinline__ void g2lds16(const void* g, void* lds) {
  __builtin_amdgcn_global_load_lds(
      (const __attribute__((address_space(1))) uint32_t*)(uintptr_t)g,
      (__attribute__((address_space(3))) uint32_t*)(uintptr_t)lds,
      16, 0, 0);
}

// ---------------------------------------------------------------------------
// Weight conversion fp32 -> bf16 (once per launch)
// ---------------------------------------------------------------------------
__global__ void cvt_weights(const float* __restrict__ w1, const float* __restrict__ w2,
                            uint16_t* __restrict__ o1, uint16_t* __restrict__ o2) {
  int i = blockIdx.x * 256 + threadIdx.x;            // grid covers 786432
  if (i < 786432) o1[i] = f2bf(w1[i]);
  if (i < 262144) o2[i] = f2bf(w2[i]);
}

// ---------------------------------------------------------------------------
// Gather: x (NCHW fp32) -> Xbf (token-major [m,512] bf16), pad+roll folded in.
// block 256 thr; z = g*100+hh, y = c-tile(8 x 64), x = ww-tile(2 x 64)
// ---------------------------------------------------------------------------
__global__ __launch_bounds__(256) void gather_kernel(
    const float* __restrict__ x, uint16_t* __restrict__ xbf, int n0) {
  __shared__ float tile[64][65];
  const int z = blockIdx.z;
  const int g = z / 100, hh = z % 100;
  const int c0 = blockIdx.y * 64, ww0 = blockIdx.x * 64;
  const int n = n0 + g;
  const int hp = (hh >= 2) ? hh - 2 : hh + 98;
  const bool hok = hp < 96;
  const int t = threadIdx.x;
  const int lane = t & 63, grp = t >> 6;

  const int ww = ww0 + lane;
  const int wp = (ww >= 2) ? ww - 2 : ww + 98;
  const bool wok = hok && (ww < 100) && (wp < 96);
  const float* xb = x + ((size_t)n * 512) * 9216 + (size_t)hp * 96 + wp;
#pragma unroll
  for (int i = 0; i < 16; ++i) {
    int c = grp + i * 4;
    tile[c][lane] = wok ? xb[(size_t)(c0 + c) * 9216] : 0.f;
  }
  __syncthreads();
#pragma unroll
  for (int i = 0; i < 16; ++i) {
    int wl = grp + i * 4;
    int www = ww0 + wl;
    if (www < 100) {
      int m = g * 10000 + hh * 100 + www;
      xbf[(size_t)m * 512 + c0 + lane] = f2bf(tile[lane][wl]);
    }
  }
}

// ---------------------------------------------------------------------------
// GEMM: D[row, col] = sum_k A[row,k]*B[col,k]  (both row-major, K contiguous)
// 128x128 tile, BK=64, 256 thr (4 waves, 2x2), mfma_f32_16x16x32_bf16.
// EPI 0: D -> bf16 Cbf[row*Ntot+col] + bias[col], rows < rowLimit (qkv proj)
// EPI 1: row = channel c, col = token; scatter fp32 to out (N,C,96,96)
//        with bias[row]; tokens >= colLimit or outside crop dropped.
// ---------------------------------------------------------------------------
template <int EPI>
__global__ __launch_bounds__(256, 2) void gemm_bf16(
    const uint16_t* __restrict__ A, const uint16_t* __restrict__ B,
    const float* __restrict__ bias, uint16_t* __restrict__ Cbf,
    float* __restrict__ Cout, int K, int Ntot, int rowLimit, int colLimit, int n0) {
  __shared__ alignas(16) uint16_t At[128 * 64];
  __shared__ alignas(16) uint16_t Bt[128 * 64];
  const int t = threadIdx.x;
  const int lane = t & 63, wv = t >> 6;
  const int wr = wv >> 1, wc = wv & 1;
  const int lr = lane & 15, lg = lane >> 4;
  const int bm = blockIdx.y, bn = blockIdx.x;

  f32x4 acc[4][4];
#pragma unroll
  for (int mi = 0; mi < 4; ++mi)
#pragma unroll
    for (int ni = 0; ni < 4; ++ni) acc[mi][ni] = (f32x4){0.f, 0.f, 0.f, 0.f};

  for (int k0 = 0; k0 < K; k0 += 64) {
#pragma unroll
    for (int i = 0; i < 4; ++i) {
      int e = i * 256 + t;                 // 16B chunk id, 1024 per tile
      int row = e >> 3, c8 = (e & 7) << 3;
      const uint16_t* ga = A + (size_t)(bm * 128 + row) * K + k0 + c8;
      const uint16_t* gb = B + (size_t)(bn * 128 + row) * K + k0 + c8;
      int ldsoff = (i * 256 + (wv << 6)) << 3;   // elements (wave-uniform)
      g2lds16(ga, &At[ldsoff]);
      g2lds16(gb, &Bt[ldsoff]);
    }
    __syncthreads();
#pragma unroll
    for (int kk = 0; kk < 64; kk += 32) {
      bf16x8 av[4], bv[4];
#pragma unroll
      for (int mi = 0; mi < 4; ++mi)
        av[mi] = *(const bf16x8*)&At[(wr * 64 + mi * 16 + lr) * 64 + kk + lg * 8];
#pragma unroll
      for (int ni = 0; ni < 4; ++ni)
        bv[ni] = *(const bf16x8*)&Bt[(wc * 64 + ni * 16 + lr) * 64 + kk + lg * 8];
#pragma unroll
      for (int mi = 0; mi < 4; ++mi)
#pragma unroll
        for (int ni = 0; ni < 4; ++ni)
          acc[mi][ni] = __builtin_amdgcn_mfma_f32_16x16x32_bf16(
              av[mi], bv[ni], acc[mi][ni], 0, 0, 0);
    }
    __syncthreads();
  }

  if (EPI == 0) {
#pragma unroll
    for (int mi = 0; mi < 4; ++mi) {
      int row = bm * 128 + wr * 64 + mi * 16 + lg * 4;
#pragma unroll
      for (int ni = 0; ni < 4; ++ni) {
        int col = bn * 128 + wc * 64 + ni * 16 + lr;
        float bb = bias[col];
#pragma unroll
        for (int r = 0; r < 4; ++r)
          if (row + r < rowLimit)
            Cbf[(size_t)(row + r) * Ntot + col] = f2bf(acc[mi][ni][r] + bb);
      }
    }
  } else {
#pragma unroll
    for (int ni = 0; ni < 4; ++ni) {
      int tok = bn * 128 + wc * 64 + ni * 16 + lr;
      if (tok < colLimit) {
        int g = tok / 10000, rem = tok % 10000;
        int hh = rem / 100, ww = rem % 100;
        if (hh >= 2 && hh < 98 && ww >= 2 && ww < 98) {
          size_t base = ((size_t)(n0 + g) * 512) * 9216 + (size_t)(hh - 2) * 96 + (ww - 2);
#pragma unroll
          for (int mi = 0; mi < 4; ++mi) {
            int c = bm * 128 + wr * 64 + mi * 16 + lg * 4;
#pragma unroll
            for (int r = 0; r < 4; ++r)
              Cout[base + (size_t)(c + r) * 9216] = acc[mi][ni][r] + bias[c + r];
          }
        }
      }
    }
  }
}

// ---------------------------------------------------------------------------
// Attention: 1 block/window, 128 thr = (head h = t/16, query qi = t%16).
// LDS-stage the 16 qkv rows (16 x 1536 bf16 = 48KB); mask from x ch0 on the
// fly (doubly-rolled => total shift 4). fp32 VALU softmax-attention.
// ---------------------------------------------------------------------------
__global__ __launch_bounds__(128) void attn_kernel(
    const uint16_t* __restrict__ qkv, const float* __restrict__ x,
    uint16_t* __restrict__ obuf, int n0) {
  __shared__ alignas(16) uint16_t sq[16][1536];
  __shared__ float smask[16];
  const int b = blockIdx.x;
  const int g = b / 625, wid = b % 625;
  const int ib = wid / 25, jb = wid % 25;
  const int t = threadIdx.x;
  const int mbase = g * 10000 + ib * 400 + jb * 4;

#pragma unroll
  for (int it = 0; it < 24; ++it) {
    int e = it * 128 + t;                  // 16B chunk; 192/row, 3072 total
    int l = e / 192;
    int off = (e - l * 192) * 8;
    int m = mbase + (l >> 2) * 100 + (l & 3);
    *(uint4*)&sq[l][off] = *(const uint4*)&qkv[(size_t)m * 1536 + off];
  }
  if (t < 16) {
    int hh = ib * 4 + (t >> 2), ww = jb * 4 + (t & 3);
    int a = (hh >= 4) ? hh - 4 : hh + 96;
    int c = (ww >= 4) ? ww - 4 : ww + 96;
    smask[t] = (a < 96 && c < 96)
                   ? x[((size_t)(n0 + g) * 512) * 9216 + (size_t)a * 96 + c]
                   : 0.f;
  }
  __syncthreads();

  const int h = t >> 4, qi = t & 15;
  float q[64];
#pragma unroll
  for (int d8 = 0; d8 < 8; ++d8) {
    u16x8 v = *(const u16x8*)&sq[qi][h * 64 + d8 * 8];
#pragma unroll
    for (int j = 0; j < 8; ++j) q[d8 * 8 + j] = bf2f(v[j]);
  }
  float s[16];
  float mx = -1e30f;
#pragma unroll
  for (int ki = 0; ki < 16; ++ki) {
    float a = 0.f;
#pragma unroll
    for (int d8 = 0; d8 < 8; ++d8) {
      u16x8 kv = *(const u16x8*)&sq[ki][512 + h * 64 + d8 * 8];
#pragma unroll
      for (int j = 0; j < 8; ++j) a += q[d8 * 8 + j] * bf2f(kv[j]);
    }
    s[ki] = a * 0.125f + smask[ki];
    mx = fmaxf(mx, s[ki]);
  }
  float sum = 0.f;
#pragma unroll
  for (int ki = 0; ki < 16; ++ki) { s[ki] = __expf(s[ki] - mx); sum += s[ki]; }
  const float inv = 1.f / sum;
  float o[64];
#pragma unroll
  for (int d = 0; d < 64; ++d) o[d] = 0.f;
#pragma unroll
  for (int ki = 0; ki < 16; ++ki) {
    float w = s[ki] * inv;
#pragma unroll
    for (int d8 = 0; d8 < 8; ++d8) {
      u16x8 vv = *(const u16x8*)&sq[ki][1024 + h * 64 + d8 * 8];
#pragma unroll
      for (int j = 0; j < 8; ++j) o[d8 * 8 + j] += w * bf2f(vv[j]);
    }
  }
  const int m = mbase + (qi >> 2) * 100 + (qi & 3);
#pragma unroll
  for (int d8 = 0; d8 < 8; ++d8) {
    alignas(16) uint16_t tmp[8];
#pragma unroll
    for (int j = 0; j < 8; ++j) tmp[j] = f2bf(o[d8 * 8 + j]);
    *(uint4*)&obuf[(size_t)m * 512 + h * 64 + d8 * 8] = *(uint4*)tmp;
  }
}

// ---------------------------------------------------------------------------
extern "C" void kernel_launch(void* const* d_in, const int* in_sizes, int n_in,
                              void* d_out, int out_size, void* d_ws, size_t ws_size,
                              hipStream_t stream) {
  const float* x    = (const float*)d_in[0];
  const float* wq   = (const float*)d_in[1];
  const float* bq   = (const float*)d_in[2];
  const float* wo   = (const float*)d_in[3];
  const float* bo   = (const float*)d_in[4];
  float* out = (float*)d_out;
  uint8_t* ws = (uint8_t*)d_ws;

  uint16_t* wq_bf = (uint16_t*)ws;                    // 1536*512*2 = 1572864
  uint16_t* wo_bf = (uint16_t*)(ws + 1572864);        // 512*512*2  = 524288
  uint8_t* bufbase = ws + 2097152;

  // chunk size: G images per chunk, buffers Mpad*(1024 + 3072) bytes
  int G = 16;
  while (G > 1) {
    int Mg = G * 10000;
    int Mp = ((Mg + 127) / 128) * 128;
    size_t need = (size_t)2097152 + (size_t)Mp * 4096;
    if (need <= ws_size) break;
    G >>= 1;
  }
  const int Mg = G * 10000;
  const int Mp = ((Mg + 127) / 128) * 128;
  uint16_t* xo   = (uint16_t*)bufbase;                          // Mp*512 bf16 (X, then O)
  uint16_t* qkvb = (uint16_t*)(bufbase + (size_t)Mp * 1024);    // Mp*1536 bf16

  cvt_weights<<<dim3(3072), dim3(256), 0, stream>>>(wq, wo, wq_bf, wo_bf);

  for (int n0 = 0; n0 < 16; n0 += G) {
    gather_kernel<<<dim3(2, 8, G * 100), dim3(256), 0, stream>>>(x, xo, n0);
    // qkv = X @ Wqkv^T + b  -> bf16 [Mg, 1536]
    gemm_bf16<0><<<dim3(12, Mp / 128), dim3(256), 0, stream>>>(
        xo, wq_bf, bq, qkvb, nullptr, 512, 1536, Mg, 0, 0);
    // per-window attention -> O bf16 [Mg, 512] (reuses xo)
    attn_kernel<<<dim3(G * 625), dim3(128), 0, stream>>>(qkvb, x, xo, n0);
    // out^T[c, m] = Wout @ O^T + b, scattered to (N,C,96,96)
    gemm_bf16<1><<<dim3(Mp / 128, 4), dim3(256), 0, stream>>>(
        wo_bf, xo, bo, nullptr, out, 512, 0, 512, Mg, n0);
  }
  (void)in_sizes; (void)n_in; (void)out_size;
}